// Round 5
// baseline (235.461 us; speedup 1.0000x reference)
//
#include <hip/hip_runtime.h>

typedef float f32x4 __attribute__((ext_vector_type(4)));
typedef long i64;

#define FP8_MAX 448.0f

// ---------------------------------------------------------------------------
// Activation quant: per (row, 128-elem K-block): s = max|x|/448, q = fp8(x/s).
// Writes xq [M][K] fp8 bytes and xst TRANSPOSED scales [K/128][M].
// ---------------------------------------------------------------------------
__global__ __launch_bounds__(256) void act_quant_k(const float* __restrict__ x,
                                                   unsigned char* __restrict__ xq,
                                                   float* __restrict__ xst,
                                                   int M, int K) {
    const int t   = threadIdx.x;
    const int qb  = blockIdx.x * 8 + (t >> 5);   // global 128-block id
    const int l32 = t & 31;
    const int row = qb >> 5;                     // K/128 == 32 blocks per row
    const int kb  = qb & 31;
    const size_t base = (size_t)row * K + (size_t)kb * 128 + (size_t)l32 * 4;

    float4 v = *(const float4*)(x + base);
    float am = fmaxf(fmaxf(fabsf(v.x), fabsf(v.y)), fmaxf(fabsf(v.z), fabsf(v.w)));
#pragma unroll
    for (int off = 1; off < 32; off <<= 1)
        am = fmaxf(am, __shfl_xor(am, off, 64));

    const float s = am / FP8_MAX;                // fp32 IEEE div, matches reference
    const float q0 = v.x / s, q1 = v.y / s, q2 = v.z / s, q3 = v.w / s;
    int p = __builtin_amdgcn_cvt_pk_fp8_f32(q0, q1, 0, false);
    p     = __builtin_amdgcn_cvt_pk_fp8_f32(q2, q3, p, true);
    *(int*)(xq + base) = p;
    if (l32 == 0) xst[(size_t)kb * M + row] = s;
}

// ---------------------------------------------------------------------------
// Weight fp32 -> fp8 byte conversion (values already on the e4m3 grid: exact).
// ---------------------------------------------------------------------------
__global__ __launch_bounds__(256) void wq_cvt_k(const float* __restrict__ w,
                                                unsigned char* __restrict__ wq) {
    const size_t i = ((size_t)blockIdx.x * 256 + threadIdx.x) * 4;
    float4 v = *(const float4*)(w + i);
    int p = __builtin_amdgcn_cvt_pk_fp8_f32(v.x, v.y, 0, false);
    p     = __builtin_amdgcn_cvt_pk_fp8_f32(v.z, v.w, p, true);
    *(int*)(wq + i) = p;
}

// ---------------------------------------------------------------------------
// Block-scaled fp8 GEMM, 128x128 tile, BK=64, 4 waves (64x64 each, 4x4 frags
// of 16x16x32 fp8 MFMA). T4 pipeline: ring-4 LDS buffers, depth-3 prefetch,
// counted s_waitcnt vmcnt(9) (never 0 in steady state), one raw s_barrier per
// 64-K tile. Fold scales (xst) are staged into LDS via the same counted
// global_load_lds queue; FOLD consumes them via ds_read (lgkmcnt) so no
// register-consumed global load ever forces a vmcnt drain.
// Per 128-K scale block: exact fp8 partial sums in accB (first MFMA uses a
// persistent zero C operand), folded into accM with a_s[m,kb]*w_s[nb,kb].
//
// LDS swizzle (both-sides, rule 21): logical [128 rows][64B];
// physical byte = row*64 + (col ^ (((row>>1)&3)<<4)). Staging keeps the LDS
// dest LINEAR and pre-swizzles the per-lane GLOBAL source column; ds_read
// applies the same XOR.
//
// vmcnt bookkeeping (per wave): even tiles stage 4 loads, odd tiles 5 (4 data
// + 1 scale). At tile t's sync, in-flight = tiles t..t+2 = 13 (even) or 14
// (odd); vmcnt(9) retires exactly tile t. Tail: 9, 9, 5, 0.
// ---------------------------------------------------------------------------
__global__ __launch_bounds__(256) void gemm_fp8_blk(
    const unsigned char* __restrict__ Aq,   // [M][K] fp8
    const unsigned char* __restrict__ Bq,   // [N][K] fp8
    const float* __restrict__ xst,          // [K/128][M] act scales (transposed)
    const float* __restrict__ wsc,          // [N/128][K/128] weight scales
    float* __restrict__ C, int M, int N, int K) {
    __shared__ unsigned char As[4][8192];   // ring: [buf][128 rows x 64 B]
    __shared__ unsigned char Bs[4][8192];
    __shared__ float Ss[2][128];            // fold scales, 2-slot ring

    const int t    = threadIdx.x;
    const int lane = t & 63;
    const int wave = t >> 6;            // 0..3
    const int wr   = wave >> 1;         // wave row (0..1)
    const int wc   = wave & 1;          // wave col (0..1)
    const int bm   = blockIdx.y * 128;
    const int bn   = blockIdx.x * 128;
    const int KBLK = K >> 7;            // 32 scale blocks (64 tiles of 64-K)
    const int nb   = bn >> 7;

    // staging: 256 threads x 16B = 4096B = 64 rows x 64B per issue; 2/operand
    const int srow   = t >> 2;          // 0..63
    const int scolsw = (((t & 3) ^ ((t >> 3) & 3)) << 4);   // pre-swizzled src col
    const unsigned char* gA = Aq + (size_t)(bm + srow) * K + scolsw;
    const unsigned char* gB = Bq + (size_t)(bn + srow) * K + scolsw;
    const float* gS = xst + bm + ((wave & 1) << 6) + lane;  // + kb*M per stage
    const int ldsoff = wave * 1024;     // wave-uniform LDS base (+ lane*16 by HW)
    const int sSoff  = (wave & 1) << 8; // 0 or 256 B (waves 0/2 dup 1/3: benign)

    // fragment read addressing (swizzled)
    const int r15 = lane & 15;
    const int g   = lane >> 4;                    // k-group 0..3
    const int sX  = (r15 >> 1) & 3;               // (row>>1)&3, row-const per lane
    const int sub = (g & 1) << 3;                 // 0 or 8 bytes within 16B unit
    const int c0  = g >> 1;                       // logical col16 at ks=0
    const int pcs[2] = { ((c0 ^ sX) << 4) + sub,
                         (((c0 + 2) ^ sX) << 4) + sub };
    const int aBase = (wr * 64 + r15) * 64;
    const int bBase = (wc * 64 + r15) * 64;

#define STAGE_D(BUF, T) do {                                                      \
        const int k0_ = (T) << 6;                                                 \
        __builtin_amdgcn_global_load_lds(                                         \
            (const __attribute__((address_space(1))) void*)(gA + k0_),            \
            (__attribute__((address_space(3))) void*)(&As[BUF][0] + ldsoff), 16, 0, 0); \
        __builtin_amdgcn_global_load_lds(                                         \
            (const __attribute__((address_space(1))) void*)(gA + (size_t)64 * K + k0_), \
            (__attribute__((address_space(3))) void*)(&As[BUF][4096] + ldsoff), 16, 0, 0); \
        __builtin_amdgcn_global_load_lds(                                         \
            (const __attribute__((address_space(1))) void*)(gB + k0_),            \
            (__attribute__((address_space(3))) void*)(&Bs[BUF][0] + ldsoff), 16, 0, 0); \
        __builtin_amdgcn_global_load_lds(                                         \
            (const __attribute__((address_space(1))) void*)(gB + (size_t)64 * K + k0_), \
            (__attribute__((address_space(3))) void*)(&Bs[BUF][4096] + ldsoff), 16, 0, 0); \
    } while (0)

#define STAGE_S(SLOT, KB)                                                         \
        __builtin_amdgcn_global_load_lds(                                         \
            (const __attribute__((address_space(1))) void*)(gS + (size_t)(KB) * M), \
            (__attribute__((address_space(3))) void*)((unsigned char*)&Ss[SLOT][0] + sSoff), \
            4, 0, 0)

#define SYNC(N_) do {                                                             \
        asm volatile("s_waitcnt vmcnt(" #N_ ")" ::: "memory");                    \
        __builtin_amdgcn_s_barrier();                                             \
        asm volatile("" ::: "memory");                                            \
    } while (0)

#define COMPUTE(BUF, FIRST) do {                                                  \
        _Pragma("unroll")                                                         \
        for (int ks = 0; ks < 2; ++ks) {                                          \
            const int pc = pcs[ks];                                               \
            i64 a_[4], b_[4];                                                     \
            _Pragma("unroll")                                                     \
            for (int i = 0; i < 4; ++i) {                                         \
                a_[i] = *(const i64*)&As[BUF][aBase + i * 1024 + pc];             \
                b_[i] = *(const i64*)&Bs[BUF][bBase + i * 1024 + pc];             \
            }                                                                     \
            _Pragma("unroll")                                                     \
            for (int i = 0; i < 4; ++i)                                           \
                _Pragma("unroll")                                                 \
                for (int j = 0; j < 4; ++j)                                       \
                    accB[i][j] = __builtin_amdgcn_mfma_f32_16x16x32_fp8_fp8(      \
                        a_[i], b_[j], ((FIRST) && ks == 0) ? z4 : accB[i][j],     \
                        0, 0, 0);                                                 \
        }                                                                         \
    } while (0)

#define FOLD(SLOT, KB) do {                                                       \
        const float wsv_ = wsc[nb * KBLK + (KB)];                                 \
        const float* sp_ = &Ss[SLOT][wr * 64 + (g << 2)];                         \
        _Pragma("unroll")                                                         \
        for (int i = 0; i < 4; ++i) {                                             \
            f32x4 sc_ = (*(const f32x4*)(sp_ + i * 16)) * wsv_;                   \
            _Pragma("unroll")                                                     \
            for (int j = 0; j < 4; ++j)                                           \
                accM[i][j] += accB[i][j] * sc_;                                   \
        }                                                                         \
    } while (0)

    f32x4 accM[4][4] = {};
    f32x4 accB[4][4];                       // init'd by z4-C MFMA, no reg writes
    const f32x4 z4 = {0.f, 0.f, 0.f, 0.f};

    // prologue: tiles 0,1,2 in flight (4 + 5 + 4 = 13 loads/wave)
    STAGE_D(0, 0);
    STAGE_D(1, 1); STAGE_S(0, 0);
    STAGE_D(2, 2);

#pragma unroll 1
    for (int q = 0; q < 15; ++q) {
        const int t0  = q << 2;   // tile of sub-phase 0 this quad
        const int kb0 = q << 1;   // scale block of tiles t0, t0+1
        SYNC(9); STAGE_D(3, t0 + 3); STAGE_S(1, kb0 + 1); COMPUTE(0, true);
        SYNC(9); STAGE_D(0, t0 + 4);                      COMPUTE(1, false); FOLD(0, kb0);
        SYNC(9); STAGE_D(1, t0 + 5); STAGE_S(0, kb0 + 2); COMPUTE(2, true);
        SYNC(9); STAGE_D(2, t0 + 6);                      COMPUTE(3, false); FOLD(1, kb0 + 1);
    }
    // tail quad: tiles 60..63, only tile 63 left to stage
    SYNC(9); STAGE_D(3, 63); STAGE_S(1, 31); COMPUTE(0, true);
    SYNC(9);                                 COMPUTE(1, false); FOLD(0, 30);
    SYNC(5);                                 COMPUTE(2, true);
    SYNC(0);                                 COMPUTE(3, false); FOLD(1, 31);

    // C write: row = (lane>>4)*4 + reg, col = lane&15 (verified C/D layout)
    const int cm = bm + wr * 64 + (g << 2);
    const int cn = bn + wc * 64 + r15;
#pragma unroll
    for (int i = 0; i < 4; ++i)
#pragma unroll
        for (int j = 0; j < 4; ++j) {
            float* cp = C + (size_t)(cm + i * 16) * N + (cn + j * 16);
#pragma unroll
            for (int r = 0; r < 4; ++r) cp[(size_t)r * N] = accM[i][j][r];
        }
#undef STAGE_D
#undef STAGE_S
#undef SYNC
#undef COMPUTE
#undef FOLD
}

extern "C" void kernel_launch(void* const* d_in, const int* in_sizes, int n_in,
                              void* d_out, int out_size, void* d_ws, size_t ws_size,
                              hipStream_t stream) {
    const float* x   = (const float*)d_in[0];   // [4096][4096] fp32
    const float* wqf = (const float*)d_in[1];   // [4096][4096] fp32 (fp8-grid values)
    const float* wsc = (const float*)d_in[2];   // [32][32] fp32
    float* out = (float*)d_out;

    const int M = 4096, N = 4096, K = 4096;

    unsigned char* xq  = (unsigned char*)d_ws;                       // 16 MB
    unsigned char* wq8 = (unsigned char*)d_ws + (size_t)M * K;       // 16 MB
    float* xst = (float*)((unsigned char*)d_ws + (size_t)M * K + (size_t)N * K); // 512 KB

    act_quant_k<<<M * (K / 128) / 8, 256, 0, stream>>>(x, xq, xst, M, K);
    wq_cvt_k<<<(N / 4) * (K / 256), 256, 0, stream>>>(wqf, wq8);
    dim3 grid(N / 128, M / 128);
    gemm_fp8_blk<<<grid, 256, 0, stream>>>(xq, wq8, xst, wsc, out, M, N, K);
}

// Round 6
// 173.357 us; speedup vs baseline: 1.3582x; 1.3582x over previous
//
#include <hip/hip_runtime.h>

typedef float f32x4 __attribute__((ext_vector_type(4)));
typedef long i64;

#define FP8_MAX 448.0f
#define AS1 __attribute__((address_space(1)))
#define AS3 __attribute__((address_space(3)))

// ---------------------------------------------------------------------------
// Activation quant: per (row, 128-elem K-block): s = max|x|/448, q = fp8(x/s).
// Writes xq [M][K] fp8 bytes and xst TRANSPOSED scales [K/128][M].
// ---------------------------------------------------------------------------
__global__ __launch_bounds__(256) void act_quant_k(const float* __restrict__ x,
                                                   unsigned char* __restrict__ xq,
                                                   float* __restrict__ xst,
                                                   int M, int K) {
    const int t   = threadIdx.x;
    const int qb  = blockIdx.x * 8 + (t >> 5);   // global 128-block id
    const int l32 = t & 31;
    const int row = qb >> 5;                     // K/128 == 32 blocks per row
    const int kb  = qb & 31;
    const size_t base = (size_t)row * K + (size_t)kb * 128 + (size_t)l32 * 4;

    float4 v = *(const float4*)(x + base);
    float am = fmaxf(fmaxf(fabsf(v.x), fabsf(v.y)), fmaxf(fabsf(v.z), fabsf(v.w)));
#pragma unroll
    for (int off = 1; off < 32; off <<= 1)
        am = fmaxf(am, __shfl_xor(am, off, 64));

    const float s = am / FP8_MAX;                // fp32 IEEE div, matches reference
    const float q0 = v.x / s, q1 = v.y / s, q2 = v.z / s, q3 = v.w / s;
    int p = __builtin_amdgcn_cvt_pk_fp8_f32(q0, q1, 0, false);
    p     = __builtin_amdgcn_cvt_pk_fp8_f32(q2, q3, p, true);
    *(int*)(xq + base) = p;
    if (l32 == 0) xst[(size_t)kb * M + row] = s;
}

// ---------------------------------------------------------------------------
// Weight fp32 -> fp8 byte conversion (values already on the e4m3 grid: exact).
// ---------------------------------------------------------------------------
__global__ __launch_bounds__(256) void wq_cvt_k(const float* __restrict__ w,
                                                unsigned char* __restrict__ wq) {
    const size_t i = ((size_t)blockIdx.x * 256 + threadIdx.x) * 4;
    float4 v = *(const float4*)(w + i);
    int p = __builtin_amdgcn_cvt_pk_fp8_f32(v.x, v.y, 0, false);
    p     = __builtin_amdgcn_cvt_pk_fp8_f32(v.z, v.w, p, true);
    *(int*)(wq + i) = p;
}

// ---------------------------------------------------------------------------
// 256x256-tile 8-phase fp8 block-dequant GEMM (m201 template port).
// 8 waves (2Mx4N), per-wave 128x64 out = 8x4 frags of 16x16x32 fp8 MFMA.
// Iter = K=128 = one scale block = 2 K-steps of BK=64; 4 phases per K-step,
// each phase = one m-quadrant (2 m-frags x 4 n-frags x 2 ks = 16 MFMA).
// Ring-3 K-step LDS buffers; counted vmcnt(5)/vmcnt(4) per K-step, never 0
// in steady state. Per-phase fold: accM += (fresh z4-C MFMA partials) *
// (a_s row vec * w_s scalar) -- exact fp8 partial sums, fp32 scale fold.
//
// LDS swizzle (both-sides, rule 21): logical [256 rows][64B]; physical byte
// = row*64 + (col ^ (((row>>1)&3)<<4)). Staging keeps the LDS dest LINEAR
// and pre-swizzles the per-lane GLOBAL source column; ds_read applies the
// same XOR.
//
// vmcnt bookkeeping (per wave, per-iter issue order [scale_{i+1}, K2i+2 x4,
// K2i+3 x4] = 9): end-P3 outstanding 9 -> vmcnt(5) retires K2i+1; end-P7
// outstanding 9 -> vmcnt(4) retires scale_{i+1}+K2i+2. Tail iter 31: no
// issues, vmcnt(0) at P3, none at P7.
// ---------------------------------------------------------------------------
__global__ __launch_bounds__(512, 2) void gemm_fp8_blk(
    const unsigned char* __restrict__ Aq,   // [M][K] fp8
    const unsigned char* __restrict__ Bq,   // [N][K] fp8
    const float* __restrict__ xst,          // [K/128][M] act scales (transposed)
    const float* __restrict__ wsc,          // [N/128][K/128] weight scales
    float* __restrict__ C, int M, int N, int K) {
    __shared__ unsigned char As[3 * 16384];  // ring-3 [256 rows x 64 B]
    __shared__ unsigned char Bs[3 * 16384];
    __shared__ float Ss[512];                // 2 scale slots x 256 rows

    const int t    = threadIdx.x;
    const int lane = t & 63;
    const int wave = t >> 6;            // 0..7
    const int wr   = wave >> 2;         // wave row (0..1) -> rows wr*128
    const int wc   = wave & 3;          // wave col (0..3) -> cols wc*64
    const int bm   = blockIdx.y * 256;
    const int bn   = blockIdx.x * 256;

    // staging: 512 threads x 16B = 8KB = 128 rows x 64B per issue; 2/op/K-step
    const int srow   = t >> 2;          // 0..127
    const int scolsw = (((t & 3) ^ ((t >> 3) & 3)) << 4);   // pre-swizzled src col
    const unsigned char* gA = Aq + (size_t)(bm + srow) * K + scolsw;
    const unsigned char* gB = Bq + (size_t)(bn + srow) * K + scolsw;
    const float* gS = xst + bm + ((wave & 3) << 6) + lane;  // + kb*M per stage
    const int ldsoff = wave << 10;      // wave-uniform LDS base (+ lane*16 by HW)
    const int sSoff  = (wave & 3) << 8; // waves 4-7 duplicate 0-3 (same data)

    // fragment read addressing (swizzled)
    const int r15 = lane & 15;
    const int g   = lane >> 4;                    // k-group 0..3
    const int sX  = (r15 >> 1) & 3;               // (row>>1)&3, row-const per lane
    const int sub = (g & 1) << 3;                 // 0 or 8 bytes within 16B unit
    const int c0  = g >> 1;                       // logical col16 at ks=0
    const int pc0 = ((c0 ^ sX) << 4) + sub;
    const int pc1 = (((c0 + 2) ^ sX) << 4) + sub;
    const int aBase = (wr * 128 + r15) * 64;      // + m*1024 per frag
    const int bBase = (wc * 64 + r15) * 64;       // + n*1024 per frag
    const int ssIdx = wr * 128 + (g << 2);        // float index into Ss slot

    const unsigned char* AsG = As;
    const unsigned char* BsG = Bs;
    const float* wscp = wsc + ((bn >> 7) + (wc >> 1)) * 32;  // wave-uniform

#define STG_A(WOFF, KS, HALF)                                                   \
    __builtin_amdgcn_global_load_lds(                                           \
        (const AS1 void*)(gA + (size_t)(HALF) * 128 * K + ((size_t)(KS) << 6)), \
        (AS3 void*)(As + (WOFF) + (HALF) * 8192 + ldsoff), 16, 0, 0)
#define STG_B(WOFF, KS, HALF)                                                   \
    __builtin_amdgcn_global_load_lds(                                           \
        (const AS1 void*)(gB + (size_t)(HALF) * 128 * K + ((size_t)(KS) << 6)), \
        (AS3 void*)(Bs + (WOFF) + (HALF) * 8192 + ldsoff), 16, 0, 0)
#define STG_S(KB)                                                               \
    __builtin_amdgcn_global_load_lds(                                           \
        (const AS1 void*)(gS + (size_t)(KB) * M),                               \
        (AS3 void*)((unsigned char*)Ss + (((KB) & 1) << 10) + sSoff), 4, 0, 0)
#define VMCNT(N_) asm volatile("s_waitcnt vmcnt(" #N_ ")" ::: "memory")

#define PHASE(OFF, Q, RDB, STAGE_STMT, END_STMT) do {                           \
    i64 pa[2][2];                                                               \
    _Pragma("unroll")                                                           \
    for (int mm = 0; mm < 2; ++mm) {                                            \
        pa[mm][0] = *(const i64*)(AsG + (OFF) + aBase + ((2*(Q)+mm) << 10) + pc0); \
        pa[mm][1] = *(const i64*)(AsG + (OFF) + aBase + ((2*(Q)+mm) << 10) + pc1); \
    }                                                                           \
    if (RDB) {                                                                  \
        _Pragma("unroll")                                                       \
        for (int n = 0; n < 4; ++n) {                                           \
            pb[n][0] = *(const i64*)(BsG + (OFF) + bBase + (n << 10) + pc0);    \
            pb[n][1] = *(const i64*)(BsG + (OFF) + bBase + (n << 10) + pc1);    \
        }                                                                       \
    }                                                                           \
    f32x4 sA0 = *(const f32x4*)(Ss + slB + ssIdx + ((2*(Q)) << 4));             \
    f32x4 sA1 = *(const f32x4*)(Ss + slB + ssIdx + ((2*(Q)+1) << 4));           \
    STAGE_STMT;                                                                 \
    __builtin_amdgcn_s_barrier();                                               \
    __builtin_amdgcn_s_setprio(1);                                              \
    f32x4 q0[4], q1[4];                                                         \
    _Pragma("unroll")                                                           \
    for (int n = 0; n < 4; ++n) {                                               \
        q0[n] = __builtin_amdgcn_mfma_f32_16x16x32_fp8_fp8(pa[0][0], pb[n][0], z4, 0, 0, 0); \
        q1[n] = __builtin_amdgcn_mfma_f32_16x16x32_fp8_fp8(pa[1][0], pb[n][0], z4, 0, 0, 0); \
    }                                                                           \
    _Pragma("unroll")                                                           \
    for (int n = 0; n < 4; ++n) {                                               \
        q0[n] = __builtin_amdgcn_mfma_f32_16x16x32_fp8_fp8(pa[0][1], pb[n][1], q0[n], 0, 0, 0); \
        q1[n] = __builtin_amdgcn_mfma_f32_16x16x32_fp8_fp8(pa[1][1], pb[n][1], q1[n], 0, 0, 0); \
    }                                                                           \
    __builtin_amdgcn_s_setprio(0);                                              \
    {                                                                           \
        f32x4 sc0 = sA0 * wsv_it, sc1 = sA1 * wsv_it;                           \
        _Pragma("unroll")                                                       \
        for (int n = 0; n < 4; ++n) {                                           \
            accM[2*(Q)][n]   += q0[n] * sc0;                                    \
            accM[2*(Q)+1][n] += q1[n] * sc1;                                    \
        }                                                                       \
    }                                                                           \
    END_STMT;                                                                   \
    __builtin_amdgcn_s_barrier();                                               \
} while (0)

#define KSTEP(OFF, WOFF, KNEW, SCKB, DOS, ENDW) do {                            \
    i64 pb[4][2];                                                               \
    PHASE(OFF, 0, 1, { if (DOS) { if ((SCKB) >= 0) STG_S(SCKB); STG_A(WOFF, KNEW, 0); } }, ((void)0)); \
    PHASE(OFF, 1, 0, { if (DOS) STG_A(WOFF, KNEW, 1); }, ((void)0));            \
    PHASE(OFF, 2, 0, { if (DOS) STG_B(WOFF, KNEW, 0); }, ((void)0));            \
    PHASE(OFF, 3, 0, { if (DOS) STG_B(WOFF, KNEW, 1); }, ENDW);                 \
} while (0)

    f32x4 accM[8][4] = {};
    const f32x4 z4 = {0.f, 0.f, 0.f, 0.f};

    // prologue: queue = [scale0, K0 x4, K1 x4]; retire scale0+K0.
    STG_S(0);
    STG_A(0, 0, 0); STG_A(0, 0, 1); STG_B(0, 0, 0); STG_B(0, 0, 1);
    STG_A(16384, 1, 0); STG_A(16384, 1, 1); STG_B(16384, 1, 0); STG_B(16384, 1, 1);
    VMCNT(4);
    __builtin_amdgcn_s_barrier();

    int oA = 0, oB = 16384, oW = 32768;   // ring-3 byte offsets
#pragma unroll 1
    for (int it2 = 0; it2 < 31; ++it2) {
        const float wsv_it = wscp[it2];
        const int slB = (it2 & 1) << 8;   // float offset of scale slot
        KSTEP(oA, oW, 2 * it2 + 2, it2 + 1, 1, VMCNT(5));
        KSTEP(oB, oA, 2 * it2 + 3, -1, 1, VMCNT(4));
        const int tmp = oA; oA = oW; oW = oB; oB = tmp;
    }
    {   // tail iter 31: K62 (oA), K63 (oB); nothing left to stage
        const float wsv_it = wscp[31];
        const int slB = (31 & 1) << 8;
        KSTEP(oA, 0, 0, -1, 0, VMCNT(0));
        KSTEP(oB, 0, 0, -1, 0, ((void)0));
    }

    // C write: row = g*4 + reg, col = r15 within each 16x16 frag
    const int cm = bm + wr * 128 + (g << 2);
    const int cn = bn + wc * 64 + r15;
#pragma unroll
    for (int m = 0; m < 8; ++m)
#pragma unroll
        for (int n = 0; n < 4; ++n) {
            float* cp = C + (size_t)(cm + m * 16) * N + (cn + n * 16);
#pragma unroll
            for (int r = 0; r < 4; ++r) cp[(size_t)r * N] = accM[m][n][r];
        }
#undef STG_A
#undef STG_B
#undef STG_S
#undef VMCNT
#undef PHASE
#undef KSTEP
}

extern "C" void kernel_launch(void* const* d_in, const int* in_sizes, int n_in,
                              void* d_out, int out_size, void* d_ws, size_t ws_size,
                              hipStream_t stream) {
    const float* x   = (const float*)d_in[0];   // [4096][4096] fp32
    const float* wqf = (const float*)d_in[1];   // [4096][4096] fp32 (fp8-grid values)
    const float* wsc = (const float*)d_in[2];   // [32][32] fp32
    float* out = (float*)d_out;

    const int M = 4096, N = 4096, K = 4096;

    unsigned char* xq  = (unsigned char*)d_ws;                       // 16 MB
    unsigned char* wq8 = (unsigned char*)d_ws + (size_t)M * K;       // 16 MB
    float* xst = (float*)((unsigned char*)d_ws + (size_t)M * K + (size_t)N * K); // 512 KB

    act_quant_k<<<M * (K / 128) / 8, 256, 0, stream>>>(x, xq, xst, M, K);
    wq_cvt_k<<<(N / 4) * (K / 256), 256, 0, stream>>>(wqf, wq8);
    dim3 grid(N / 256, M / 256);
    gemm_fp8_blk<<<grid, 512, 0, stream>>>(xq, wq8, xst, wsc, out, M, N, K);
}